// Round 4
// baseline (663.298 us; speedup 1.0000x reference)
//
#include <hip/hip_runtime.h>
#include <cstdint>
#include <cstddef>

typedef _Float16 f16;
typedef _Float16 half8 __attribute__((ext_vector_type(8)));
typedef float floatx4 __attribute__((ext_vector_type(4)));

static constexpr size_t NB  = 16384;
static constexpr size_t DH  = 2048;
static constexpr size_t F1  = 1024;
static constexpr size_t F2  = 512;
static constexpr size_t CD  = 256;
static constexpr size_t KCB = 512;

// ---- d_out element offsets (all float32) ----
static constexpr size_t ZE_OFF  = 0;
static constexpr size_t ZQ_OFF  = NB * CD;
static constexpr size_t HR_OFF  = 2 * NB * CD;
static constexpr size_t IDX_OFF = 2 * NB * CD + NB * DH;

// ---- workspace byte offsets ----
static constexpr size_t O_W1H = 0;
static constexpr size_t O_W1L = O_W1H + F1 * DH * 2;
static constexpr size_t O_W2H = O_W1L + F1 * DH * 2;
static constexpr size_t O_W2L = O_W2H + F2 * F1 * 2;
static constexpr size_t O_W3H = O_W2L + F2 * F1 * 2;
static constexpr size_t O_W3L = O_W3H + CD * F2 * 2;
static constexpr size_t O_CBH = O_W3L + CD * F2 * 2;
static constexpr size_t O_CBL = O_CBH + KCB * CD * 2;
static constexpr size_t O_DW1 = O_CBL + KCB * CD * 2;
static constexpr size_t O_DW2 = O_DW1 + F2 * CD * 2;
static constexpr size_t O_DW3 = O_DW2 + F1 * F2 * 2;
static constexpr size_t O_SUM = O_DW3 + DH * F1 * 2;   // 4 layers x 1024 doubles
static constexpr size_t O_SQ  = O_SUM + 4 * 1024 * 8;
static constexpr size_t O_SC  = O_SQ + 4 * 1024 * 8;
static constexpr size_t O_SH  = O_SC + 4 * 1024 * 4;
static constexpr size_t O_CN  = O_SH + 4 * 1024 * 4;
static constexpr size_t O_X1F = (O_CN + 4096 + 255) & ~(size_t)255;  // [NB,F1] f32; later Y2F
static constexpr size_t O_X2F = O_X1F + NB * F1 * 4;                 // [NB,F2] f32; later Y1F
static constexpr size_t O_SB  = O_X2F + NB * F2 * 4;                 // [NB,KCB] f32

#define GLLDS(src, dst)                                                          \
    __builtin_amdgcn_global_load_lds(                                            \
        (const __attribute__((address_space(1))) void*)(src),                    \
        (__attribute__((address_space(3))) void*)(dst), 16, 0, 0)

#define VMCNT(n)  asm volatile("s_waitcnt vmcnt(" #n ")" ::: "memory")
#define LGKMCNT0  asm volatile("s_waitcnt lgkmcnt(0)" ::: "memory")

// ============================================================================
// Fused 3-product GEMM with in-staging f32->hi/lo split (+optional BN+LReLU):
// C[M,N](f32) = Ah*Bh^T + Ah*Bl^T + Al*Bh^T where (Ah,Al) are computed
// on the fly from f32 A (after optional affine+LReLU). B pre-split f16.
// BM=BN=256, BK=32, 8 waves (2Mx4N), wave tile 128x64.
// LDS per buffer: A-merged [256 rows][64 f16] (slots 0-3=H,4-7=L, XOR swz),
// BH/BL paired-row [128][64] (rows 2q,2q+1). 3 phases/K-tile, counted vmcnt.
// ============================================================================
template<bool AFF, bool BIAS, bool STATS>
__global__ __launch_bounds__(512)
void gemm3f(const float* __restrict__ Af, const f16* __restrict__ Bh_,
            const f16* __restrict__ Bl_, const float* __restrict__ scale,
            const float* __restrict__ shift, float* __restrict__ C,
            const float* __restrict__ bias, double* __restrict__ ssum,
            double* __restrict__ ssq, int M, int N, int K)
{
    __shared__ f16 sA[2][16384];
    __shared__ f16 sBH[2][8192];
    __shared__ f16 sBL[2][8192];
    const int tid = threadIdx.x, lane = tid & 63, w = tid >> 6;
    const int wr = w >> 2, wn = w & 3;
    const int row0 = blockIdx.x * 256, col0 = blockIdx.y * 256;
    const int KT = K >> 5;

    // A reg-staging geometry: 2 units, rows w*32 + i*16 + (lane>>2), kslot lane&3
    const int ar = lane >> 2, aks = lane & 3;
    const int rwA0 = w * 32 + ar, rwA1 = rwA0 + 16;
    const size_t offA0 = (size_t)(row0 + rwA0) * K + aks * 8;
    const size_t offA1 = (size_t)(row0 + rwA1) * K + aks * 8;
    const int wH0 = rwA0 * 64 + ((aks ^ (rwA0 & 7)) << 3);
    const int wL0 = rwA0 * 64 + (((aks + 4) ^ (rwA0 & 7)) << 3);
    const int wH1 = rwA1 * 64 + ((aks ^ (rwA1 & 7)) << 3);
    const int wL1 = rwA1 * 64 + (((aks + 4) ^ (rwA1 & 7)) << 3);

    // B gload_lds staging: paired-row [128][64] planes
    const int rr8 = lane >> 3, sp = lane & 7, p = sp ^ rr8;
    const size_t offB0 = (size_t)(col0 + 2 * (w * 16 + 0 + rr8) + (p >> 2)) * K + (p & 3) * 8;
    const size_t offB1 = (size_t)(col0 + 2 * (w * 16 + 8 + rr8) + (p >> 2)) * K + (p & 3) * 8;
    const int dB0 = (w * 16 + 0) * 64, dB1 = (w * 16 + 8) * 64;

    // fragment read addresses
    const int l15 = lane & 15, sl = lane >> 4;
    int rdAH[8], rdAL[8], rdB[4];
#pragma unroll
    for (int m = 0; m < 8; ++m) {
        const int rA = wr * 128 + m * 16 + l15;
        rdAH[m] = rA * 64 + ((sl ^ (rA & 7)) << 3);
        rdAL[m] = rA * 64 + (((4 + sl) ^ (rA & 7)) << 3);
    }
#pragma unroll
    for (int n = 0; n < 4; ++n) {
        const int rB = wn * 64 + n * 16 + l15;
        const int q = rB >> 1;
        rdB[n] = q * 64 + (((((rB & 1) << 2) + sl) ^ (q & 7)) << 3);
    }

    floatx4 acc[8][4];
#pragma unroll
    for (int m = 0; m < 8; ++m)
#pragma unroll
        for (int n = 0; n < 4; ++n)
#pragma unroll
            for (int j = 0; j < 4; ++j) acc[m][n][j] = 0.f;

    floatx4 u0a, u0b, u1a, u1b, sv0, sv1, hv0, hv1;

    auto cvt_write = [&](int dst) {
        half8 hh, ll;
#pragma unroll
        for (int j = 0; j < 4; ++j) {
            float v = u0a[j];
            if constexpr (AFF) { v = fmaf(v, sv0[j], hv0[j]); v = v >= 0.f ? v : 0.01f * v; }
            f16 t = (f16)v; hh[j] = t; ll[j] = (f16)(v - (float)t);
            float v2 = u0b[j];
            if constexpr (AFF) { v2 = fmaf(v2, sv1[j], hv1[j]); v2 = v2 >= 0.f ? v2 : 0.01f * v2; }
            f16 t2 = (f16)v2; hh[4 + j] = t2; ll[4 + j] = (f16)(v2 - (float)t2);
        }
        *(half8*)&sA[dst][wH0] = hh; *(half8*)&sA[dst][wL0] = ll;
#pragma unroll
        for (int j = 0; j < 4; ++j) {
            float v = u1a[j];
            if constexpr (AFF) { v = fmaf(v, sv0[j], hv0[j]); v = v >= 0.f ? v : 0.01f * v; }
            f16 t = (f16)v; hh[j] = t; ll[j] = (f16)(v - (float)t);
            float v2 = u1b[j];
            if constexpr (AFF) { v2 = fmaf(v2, sv1[j], hv1[j]); v2 = v2 >= 0.f ? v2 : 0.01f * v2; }
            f16 t2 = (f16)v2; hh[4 + j] = t2; ll[4 + j] = (f16)(v2 - (float)t2);
        }
        *(half8*)&sA[dst][wH1] = hh; *(half8*)&sA[dst][wL1] = ll;
    };

    // ---- prologue: tile 0 ----
    u0a = *(const floatx4*)(Af + offA0);     u0b = *(const floatx4*)(Af + offA0 + 4);
    u1a = *(const floatx4*)(Af + offA1);     u1b = *(const floatx4*)(Af + offA1 + 4);
    if constexpr (AFF) {
        sv0 = *(const floatx4*)(scale + aks * 8);     sv1 = *(const floatx4*)(scale + aks * 8 + 4);
        hv0 = *(const floatx4*)(shift + aks * 8);     hv1 = *(const floatx4*)(shift + aks * 8 + 4);
    }
    GLLDS(Bh_ + offB0, &sBH[0][dB0]); GLLDS(Bh_ + offB1, &sBH[0][dB1]);
    GLLDS(Bl_ + offB0, &sBL[0][dB0]); GLLDS(Bl_ + offB1, &sBL[0][dB1]);
    VMCNT(4);
    cvt_write(0);
    VMCNT(0); LGKMCNT0;
    __builtin_amdgcn_s_barrier();

    half8 afh[8], afl[8], bfh[4], bfl[4];

    for (int kt = 0; kt < KT; ++kt) {
        const int cur = kt & 1, nxt = cur ^ 1;
        const int koff = (kt + 1 < KT ? kt + 1 : kt) << 5;
        const f16* pA = sA[cur]; const f16* pBH = sBH[cur]; const f16* pBL = sBL[cur];

        // ===== phase 1 : hh =====
#pragma unroll
        for (int m = 0; m < 8; ++m) afh[m] = *(const half8*)(pA + rdAH[m]);
#pragma unroll
        for (int n = 0; n < 4; ++n) bfh[n] = *(const half8*)(pBH + rdB[n]);
        u0a = *(const floatx4*)(Af + offA0 + koff); u0b = *(const floatx4*)(Af + offA0 + koff + 4);
        u1a = *(const floatx4*)(Af + offA1 + koff); u1b = *(const floatx4*)(Af + offA1 + koff + 4);
        if constexpr (AFF) {
            sv0 = *(const floatx4*)(scale + koff + aks * 8); sv1 = *(const floatx4*)(scale + koff + aks * 8 + 4);
            hv0 = *(const floatx4*)(shift + koff + aks * 8); hv1 = *(const floatx4*)(shift + koff + aks * 8 + 4);
        }
        GLLDS(Bh_ + offB0 + koff, &sBH[nxt][dB0]); GLLDS(Bh_ + offB1 + koff, &sBH[nxt][dB1]);
        if constexpr (AFF) { VMCNT(10); } else { VMCNT(6); }   // drain BL(t)
        __builtin_amdgcn_s_barrier();
        LGKMCNT0; __builtin_amdgcn_sched_barrier(0);
        __builtin_amdgcn_s_setprio(1);
#pragma unroll
        for (int m = 0; m < 8; ++m)
#pragma unroll
            for (int n = 0; n < 4; ++n)
                acc[m][n] = __builtin_amdgcn_mfma_f32_16x16x32_f16(afh[m], bfh[n], acc[m][n], 0, 0, 0);
        __builtin_amdgcn_s_setprio(0);
        __builtin_amdgcn_s_barrier();

        // ===== phase 2 : hl =====
        VMCNT(2);                               // A f32 (+ss) landed; BH(t+1) in flight
#pragma unroll
        for (int n = 0; n < 4; ++n) bfl[n] = *(const half8*)(pBL + rdB[n]);
        cvt_write(nxt);
        GLLDS(Bl_ + offB0 + koff, &sBL[nxt][dB0]); GLLDS(Bl_ + offB1 + koff, &sBL[nxt][dB1]);
        __builtin_amdgcn_s_barrier();
        LGKMCNT0; __builtin_amdgcn_sched_barrier(0);
        __builtin_amdgcn_s_setprio(1);
#pragma unroll
        for (int m = 0; m < 8; ++m)
#pragma unroll
            for (int n = 0; n < 4; ++n)
                acc[m][n] = __builtin_amdgcn_mfma_f32_16x16x32_f16(afh[m], bfl[n], acc[m][n], 0, 0, 0);
        __builtin_amdgcn_s_setprio(0);
        __builtin_amdgcn_s_barrier();

        // ===== phase 3 : lh =====
#pragma unroll
        for (int m = 0; m < 8; ++m) afl[m] = *(const half8*)(pA + rdAL[m]);
        VMCNT(2);                               // drain BH(t+1) for next ph1
        __builtin_amdgcn_s_barrier();
        LGKMCNT0; __builtin_amdgcn_sched_barrier(0);
        __builtin_amdgcn_s_setprio(1);
#pragma unroll
        for (int m = 0; m < 8; ++m)
#pragma unroll
            for (int n = 0; n < 4; ++n)
                acc[m][n] = __builtin_amdgcn_mfma_f32_16x16x32_f16(afl[m], bfh[n], acc[m][n], 0, 0, 0);
        __builtin_amdgcn_s_setprio(0);
        __builtin_amdgcn_s_barrier();
    }
    VMCNT(0);

    // ---- epilogue ----
    const int cb0 = col0 + wn * 64;
    const int rb0 = row0 + wr * 128 + (lane >> 4) * 4;
#pragma unroll
    for (int n = 0; n < 4; ++n) {
        const int col = cb0 + n * 16 + l15;
        const float bv = BIAS ? bias[col] : 0.f;
        double sd = 0.0, sq = 0.0;
#pragma unroll
        for (int m = 0; m < 8; ++m) {
            const int row = rb0 + m * 16;
#pragma unroll
            for (int j = 0; j < 4; ++j) {
                const float v = acc[m][n][j] + bv;
                C[(size_t)(row + j) * N + col] = v;
                if (STATS) { sd += (double)v; sq += (double)v * (double)v; }
            }
        }
        if (STATS) {
            sd += __shfl_xor(sd, 16); sd += __shfl_xor(sd, 32);
            sq += __shfl_xor(sq, 16); sq += __shfl_xor(sq, 32);
            if (lane < 16) { atomicAdd(ssum + col, sd); atomicAdd(ssq + col, sq); }
        }
    }
}

// ============================================================================
// Fused 1-product GEMM (decoder): C = A*B^T from f32 A (+optional affine+
// LReLU), hi-plane only. Ring-3 buffers, 2 phases/K-tile, counted vmcnt.
// A plane paired-row [128][64]; B plane paired-row [128][64].
// ============================================================================
template<bool AFF, bool BIAS, bool STATS>
__global__ __launch_bounds__(512)
void gemm1f(const float* __restrict__ Af, const f16* __restrict__ Bh_,
            const float* __restrict__ scale, const float* __restrict__ shift,
            float* __restrict__ C, const float* __restrict__ bias,
            double* __restrict__ ssum, double* __restrict__ ssq,
            int M, int N, int K)
{
    __shared__ f16 sA[3][8192];
    __shared__ f16 sB[3][8192];
    const int tid = threadIdx.x, lane = tid & 63, w = tid >> 6;
    const int wr = w >> 2, wn = w & 3;
    const int row0 = blockIdx.x * 256, col0 = blockIdx.y * 256;
    const int KT = K >> 5;

    // A staging: paired rows, 2 units; phys q = w*16 + i*8 + (lane>>3), lslot lane&7
    const int aq = lane >> 3, alsl = lane & 7;
    const int pq0 = w * 16 + aq, pq1 = pq0 + 8;
    const int mr0 = 2 * pq0 + (alsl >> 2), mr1 = 2 * pq1 + (alsl >> 2);
    const size_t offA0 = (size_t)(row0 + mr0) * K + (alsl & 3) * 8;
    const size_t offA1 = (size_t)(row0 + mr1) * K + (alsl & 3) * 8;
    const int wA0 = pq0 * 64 + ((alsl ^ (pq0 & 7)) << 3);
    const int wA1 = pq1 * 64 + ((alsl ^ (pq1 & 7)) << 3);
    const int aks = alsl & 3;

    // B staging (gload_lds)
    const int rr8 = lane >> 3, sp = lane & 7, p = sp ^ rr8;
    const size_t offB0 = (size_t)(col0 + 2 * (w * 16 + 0 + rr8) + (p >> 2)) * K + (p & 3) * 8;
    const size_t offB1 = (size_t)(col0 + 2 * (w * 16 + 8 + rr8) + (p >> 2)) * K + (p & 3) * 8;
    const int dB0 = (w * 16 + 0) * 64, dB1 = (w * 16 + 8) * 64;

    const int l15 = lane & 15, sl = lane >> 4;
    int rdA[8], rdB[4];
#pragma unroll
    for (int m = 0; m < 8; ++m) {
        const int rA = wr * 128 + m * 16 + l15;
        const int q = rA >> 1;
        rdA[m] = q * 64 + (((((rA & 1) << 2) + sl) ^ (q & 7)) << 3);
    }
#pragma unroll
    for (int n = 0; n < 4; ++n) {
        const int rB = wn * 64 + n * 16 + l15;
        const int q = rB >> 1;
        rdB[n] = q * 64 + (((((rB & 1) << 2) + sl) ^ (q & 7)) << 3);
    }

    floatx4 acc[8][4];
#pragma unroll
    for (int m = 0; m < 8; ++m)
#pragma unroll
        for (int n = 0; n < 4; ++n)
#pragma unroll
            for (int j = 0; j < 4; ++j) acc[m][n][j] = 0.f;

    floatx4 u0a, u0b, u1a, u1b, sv0, sv1, hv0, hv1;

    auto cvt_write = [&](int dst) {
        half8 hh;
#pragma unroll
        for (int j = 0; j < 4; ++j) {
            float v = u0a[j];
            if constexpr (AFF) { v = fmaf(v, sv0[j], hv0[j]); v = v >= 0.f ? v : 0.01f * v; }
            hh[j] = (f16)v;
            float v2 = u0b[j];
            if constexpr (AFF) { v2 = fmaf(v2, sv1[j], hv1[j]); v2 = v2 >= 0.f ? v2 : 0.01f * v2; }
            hh[4 + j] = (f16)v2;
        }
        *(half8*)&sA[dst][wA0] = hh;
#pragma unroll
        for (int j = 0; j < 4; ++j) {
            float v = u1a[j];
            if constexpr (AFF) { v = fmaf(v, sv0[j], hv0[j]); v = v >= 0.f ? v : 0.01f * v; }
            hh[j] = (f16)v;
            float v2 = u1b[j];
            if constexpr (AFF) { v2 = fmaf(v2, sv1[j], hv1[j]); v2 = v2 >= 0.f ? v2 : 0.01f * v2; }
            hh[4 + j] = (f16)v2;
        }
        *(half8*)&sA[dst][wA1] = hh;
    };

    // ---- prologue: tiles 0 and 1 ----
    floatx4 q0a = *(const floatx4*)(Af + offA0), q0b = *(const floatx4*)(Af + offA0 + 4);
    floatx4 q1a = *(const floatx4*)(Af + offA1), q1b = *(const floatx4*)(Af + offA1 + 4);
    floatx4 ps0, ps1, ph0, ph1;
    if constexpr (AFF) {
        ps0 = *(const floatx4*)(scale + aks * 8); ps1 = *(const floatx4*)(scale + aks * 8 + 4);
        ph0 = *(const floatx4*)(shift + aks * 8); ph1 = *(const floatx4*)(shift + aks * 8 + 4);
    }
    GLLDS(Bh_ + offB0, &sB[0][dB0]); GLLDS(Bh_ + offB1, &sB[0][dB1]);
    {
        const int k1 = (KT > 1 ? 1 : 0) << 5;
        u0a = *(const floatx4*)(Af + offA0 + k1); u0b = *(const floatx4*)(Af + offA0 + k1 + 4);
        u1a = *(const floatx4*)(Af + offA1 + k1); u1b = *(const floatx4*)(Af + offA1 + k1 + 4);
        if constexpr (AFF) {
            sv0 = *(const floatx4*)(scale + k1 + aks * 8); sv1 = *(const floatx4*)(scale + k1 + aks * 8 + 4);
            hv0 = *(const floatx4*)(shift + k1 + aks * 8); hv1 = *(const floatx4*)(shift + k1 + aks * 8 + 4);
        }
        GLLDS(Bh_ + offB0 + k1, &sB[1][dB0]); GLLDS(Bh_ + offB1 + k1, &sB[1][dB1]);
    }
    if constexpr (AFF) { VMCNT(12); } else { VMCNT(8); }   // tile-0 A (+ss) landed
    {
        floatx4 t0 = u0a, t1 = u0b, t2 = u1a, t3 = u1b, s0 = sv0, s1 = sv1, h0 = hv0, h1 = hv1;
        u0a = q0a; u0b = q0b; u1a = q1a; u1b = q1b;
        if constexpr (AFF) { sv0 = ps0; sv1 = ps1; hv0 = ph0; hv1 = ph1; }
        cvt_write(0);
        u0a = t0; u0b = t1; u1a = t2; u1b = t3;
        if constexpr (AFF) { sv0 = s0; sv1 = s1; hv0 = h0; hv1 = h1; }
    }
    VMCNT(2);                                   // tile-1 A landed; B(1) in flight
    cvt_write(1);
    LGKMCNT0;
    __builtin_amdgcn_s_barrier();

    half8 afh[8], bfh[4];

    for (int kt = 0; kt < KT; ++kt) {
        const int cur = kt % 3, nx2 = (kt + 2) % 3;
        const int koff = (kt + 2 < KT ? kt + 2 : KT - 1) << 5;
        const f16* pA = sA[cur]; const f16* pB = sB[cur];

        // ===== phase 1 =====
#pragma unroll
        for (int m = 0; m < 8; ++m) afh[m] = *(const half8*)(pA + rdA[m]);
#pragma unroll
        for (int n = 0; n < 4; ++n) bfh[n] = *(const half8*)(pB + rdB[n]);
        u0a = *(const floatx4*)(Af + offA0 + koff); u0b = *(const floatx4*)(Af + offA0 + koff + 4);
        u1a = *(const floatx4*)(Af + offA1 + koff); u1b = *(const floatx4*)(Af + offA1 + koff + 4);
        if constexpr (AFF) {
            sv0 = *(const floatx4*)(scale + koff + aks * 8); sv1 = *(const floatx4*)(scale + koff + aks * 8 + 4);
            hv0 = *(const floatx4*)(shift + koff + aks * 8); hv1 = *(const floatx4*)(shift + koff + aks * 8 + 4);
        }
        GLLDS(Bh_ + offB0 + koff, &sB[nx2][dB0]); GLLDS(Bh_ + offB1 + koff, &sB[nx2][dB1]);
        if constexpr (AFF) { VMCNT(10); } else { VMCNT(6); }  // drain B(t+1)
        __builtin_amdgcn_s_barrier();
        LGKMCNT0; __builtin_amdgcn_sched_barrier(0);
        __builtin_amdgcn_s_setprio(1);
#pragma unroll
        for (int m = 0; m < 8; ++m)
#pragma unroll
            for (int n = 0; n < 2; ++n)
                acc[m][n] = __builtin_amdgcn_mfma_f32_16x16x32_f16(afh[m], bfh[n], acc[m][n], 0, 0, 0);
        __builtin_amdgcn_s_setprio(0);
        __builtin_amdgcn_s_barrier();

        // ===== phase 2 =====
        VMCNT(2);                               // A f32 (+ss) landed; B(t+2) in flight
        cvt_write(nx2);
        __builtin_amdgcn_s_setprio(1);
#pragma unroll
        for (int m = 0; m < 8; ++m)
#pragma unroll
            for (int n = 2; n < 4; ++n)
                acc[m][n] = __builtin_amdgcn_mfma_f32_16x16x32_f16(afh[m], bfh[n], acc[m][n], 0, 0, 0);
        __builtin_amdgcn_s_setprio(0);
        LGKMCNT0;
        __builtin_amdgcn_s_barrier();
    }
    VMCNT(0);

    const int cb0 = col0 + wn * 64;
    const int rb0 = row0 + wr * 128 + (lane >> 4) * 4;
#pragma unroll
    for (int n = 0; n < 4; ++n) {
        const int col = cb0 + n * 16 + l15;
        const float bv = BIAS ? bias[col] : 0.f;
        double sd = 0.0, sq = 0.0;
#pragma unroll
        for (int m = 0; m < 8; ++m) {
            const int row = rb0 + m * 16;
#pragma unroll
            for (int j = 0; j < 4; ++j) {
                const float v = acc[m][n][j] + bv;
                C[(size_t)(row + j) * N + col] = v;
                if (STATS) { sd += (double)v; sq += (double)v * (double)v; }
            }
        }
        if (STATS) {
            sd += __shfl_xor(sd, 16); sd += __shfl_xor(sd, 32);
            sq += __shfl_xor(sq, 16); sq += __shfl_xor(sq, 32);
            if (lane < 16) { atomicAdd(ssum + col, sd); atomicAdd(ssq + col, sq); }
        }
    }
}

__global__ void bn_finalize(const double* __restrict__ ssum, const double* __restrict__ ssq,
                            const float* __restrict__ g, const float* __restrict__ b,
                            float* __restrict__ scale, float* __restrict__ shift, int N)
{
    const int j = blockIdx.x * blockDim.x + threadIdx.x;
    if (j < N) {
        const double inv = 1.0 / (double)NB;
        const double mean = ssum[j] * inv;
        const double var  = ssq[j] * inv - mean * mean;
        const double sc   = (double)g[j] / sqrt(var + 1e-5);
        scale[j] = (float)sc;
        shift[j] = (float)((double)b[j] - mean * sc);
    }
}

// W[K,N] f32 -> T[N,K] f16 (optionally with lo residual)
template<bool SPLIT>
__global__ void transpose_split(const float* __restrict__ W, f16* __restrict__ Thi,
                                f16* __restrict__ Tlo, int K, int N)
{
    __shared__ float tile[32][33];
    const int x = threadIdx.x;
    const int y = threadIdx.y;
    const int nt = blockIdx.x * 32;
    const int kt = blockIdx.y * 32;
#pragma unroll
    for (int i = 0; i < 32; i += 8)
        tile[y + i][x] = W[(size_t)(kt + y + i) * N + nt + x];
    __syncthreads();
#pragma unroll
    for (int i = 0; i < 32; i += 8) {
        const float v = tile[x][y + i];
        const size_t o = (size_t)(nt + y + i) * K + kt + x;
        const f16 hv = (f16)v;
        Thi[o] = hv;
        if (SPLIT) Tlo[o] = (f16)(v - (float)hv);
    }
}

__global__ void cnorm_kernel(const float* __restrict__ cb, float* __restrict__ cn)
{
    const int k = blockIdx.x * blockDim.x + threadIdx.x;
    if (k < (int)KCB) {
        double s = 0.0;
        for (int d = 0; d < (int)CD; ++d) {
            const float v = cb[(size_t)d * KCB + k];
            s += (double)v * v;
        }
        cn[k] = (float)s;
    }
}

// dist[b,k] = cnorm[k] - 2*S[b,k]; first-index argmin; gather z_q
__global__ void argmin_gather(const float* __restrict__ S, const float* __restrict__ cn,
                              const float* __restrict__ cb, float* __restrict__ zq,
                              float* __restrict__ idx_out)
{
    const int lane = threadIdx.x & 63;
    const int row  = blockIdx.x * 4 + (threadIdx.x >> 6);
    const float* Sr = S + (size_t)row * KCB;
    float best = 3.4e38f;
    int bi = 0;
#pragma unroll
    for (int i = 0; i < 8; ++i) {
        const int k = lane + 64 * i;
        const float d = cn[k] - 2.f * Sr[k];
        if (d < best) { best = d; bi = k; }
    }
#pragma unroll
    for (int off = 32; off > 0; off >>= 1) {
        const float ob = __shfl_xor(best, off);
        const int   oi = __shfl_xor(bi, off);
        if (ob < best || (ob == best && oi < bi)) { best = ob; bi = oi; }
    }
    if (lane == 0) idx_out[row] = (float)bi;
#pragma unroll
    for (int i = 0; i < 4; ++i) {
        const int d = lane + 64 * i;
        zq[(size_t)row * CD + d] = cb[(size_t)d * KCB + bi];
    }
}

extern "C" void kernel_launch(void* const* d_in, const int* in_sizes, int n_in,
                              void* d_out, int out_size, void* d_ws, size_t ws_size,
                              hipStream_t stream)
{
    (void)in_sizes; (void)n_in; (void)out_size; (void)ws_size;
    const float* h   = (const float*)d_in[0];
    const float* ew1 = (const float*)d_in[1];
    const float* bg1 = (const float*)d_in[2];
    const float* bb1 = (const float*)d_in[3];
    const float* ew2 = (const float*)d_in[4];
    const float* bg2 = (const float*)d_in[5];
    const float* bb2 = (const float*)d_in[6];
    const float* ew3 = (const float*)d_in[7];
    const float* eb3 = (const float*)d_in[8];
    const float* cb  = (const float*)d_in[9];
    const float* dw1 = (const float*)d_in[10];
    const float* dg1 = (const float*)d_in[11];
    const float* db1 = (const float*)d_in[12];
    const float* dw2 = (const float*)d_in[13];
    const float* dg2 = (const float*)d_in[14];
    const float* db2 = (const float*)d_in[15];
    const float* dw3 = (const float*)d_in[16];
    const float* db3 = (const float*)d_in[17];

    char* ws = (char*)d_ws;
    float* out = (float*)d_out;

    f16* W1h = (f16*)(ws + O_W1H);
    f16* W1l = (f16*)(ws + O_W1L);
    f16* W2h = (f16*)(ws + O_W2H);
    f16* W2l = (f16*)(ws + O_W2L);
    f16* W3h = (f16*)(ws + O_W3H);
    f16* W3l = (f16*)(ws + O_W3L);
    f16* CBh = (f16*)(ws + O_CBH);
    f16* CBl = (f16*)(ws + O_CBL);
    f16* D1t = (f16*)(ws + O_DW1);
    f16* D2t = (f16*)(ws + O_DW2);
    f16* D3t = (f16*)(ws + O_DW3);
    double* sum0 = (double*)(ws + O_SUM);
    double* sq0  = (double*)(ws + O_SQ);
    float* sc0 = (float*)(ws + O_SC);
    float* sh0 = (float*)(ws + O_SH);
    float* cn  = (float*)(ws + O_CN);
    float* X1f = (float*)(ws + O_X1F);   // also Y2f
    float* X2f = (float*)(ws + O_X2F);   // also Y1f
    float* Sb  = (float*)(ws + O_SB);
    float* Y1f = X2f;
    float* Y2f = X1f;

    hipMemsetAsync(ws + O_SUM, 0, 4 * 1024 * 8 * 2, stream);

    // weight conversions
    transpose_split<true ><<<dim3(F1 / 32, DH / 32), dim3(32, 8), 0, stream>>>(ew1, W1h, W1l, DH, F1);
    transpose_split<true ><<<dim3(F2 / 32, F1 / 32), dim3(32, 8), 0, stream>>>(ew2, W2h, W2l, F1, F2);
    transpose_split<true ><<<dim3(CD / 32, F2 / 32), dim3(32, 8), 0, stream>>>(ew3, W3h, W3l, F2, CD);
    transpose_split<true ><<<dim3(KCB / 32, CD / 32), dim3(32, 8), 0, stream>>>(cb, CBh, CBl, CD, KCB);
    transpose_split<false><<<dim3(F2 / 32, CD / 32), dim3(32, 8), 0, stream>>>(dw1, D1t, nullptr, CD, F2);
    transpose_split<false><<<dim3(F1 / 32, F2 / 32), dim3(32, 8), 0, stream>>>(dw2, D2t, nullptr, F2, F1);
    transpose_split<false><<<dim3(DH / 32, F1 / 32), dim3(32, 8), 0, stream>>>(dw3, D3t, nullptr, F1, DH);

    // ---- encoder ----
    gemm3f<false, false, true><<<dim3(NB / 256, F1 / 256), 512, 0, stream>>>(
        h, W1h, W1l, nullptr, nullptr, X1f, nullptr, sum0, sq0, NB, F1, DH);
    bn_finalize<<<4, 256, 0, stream>>>(sum0, sq0, bg1, bb1, sc0, sh0, F1);

    gemm3f<true, false, true><<<dim3(NB / 256, F2 / 256), 512, 0, stream>>>(
        X1f, W2h, W2l, sc0, sh0, X2f, nullptr, sum0 + 1024, sq0 + 1024, NB, F2, F1);
    bn_finalize<<<2, 256, 0, stream>>>(sum0 + 1024, sq0 + 1024, bg2, bb2, sc0 + 1024, sh0 + 1024, F2);

    gemm3f<true, true, false><<<dim3(NB / 256, CD / 256), 512, 0, stream>>>(
        X2f, W3h, W3l, sc0 + 1024, sh0 + 1024, out + ZE_OFF, eb3, nullptr, nullptr, NB, CD, F2);

    // ---- quantize ----
    cnorm_kernel<<<2, 256, 0, stream>>>(cb, cn);
    gemm3f<false, false, false><<<dim3(NB / 256, KCB / 256), 512, 0, stream>>>(
        out + ZE_OFF, CBh, CBl, nullptr, nullptr, Sb, nullptr, nullptr, nullptr, NB, KCB, CD);
    argmin_gather<<<NB / 4, 256, 0, stream>>>(Sb, cn, cb, out + ZQ_OFF, out + IDX_OFF);

    // ---- decoder ----
    gemm1f<false, false, true><<<dim3(NB / 256, F2 / 256), 512, 0, stream>>>(
        out + ZQ_OFF, D1t, nullptr, nullptr, Y1f, nullptr, sum0 + 2048, sq0 + 2048, NB, F2, CD);
    bn_finalize<<<2, 256, 0, stream>>>(sum0 + 2048, sq0 + 2048, dg1, db1, sc0 + 2048, sh0 + 2048, F2);

    gemm1f<true, false, true><<<dim3(NB / 256, F1 / 256), 512, 0, stream>>>(
        Y1f, D2t, sc0 + 2048, sh0 + 2048, Y2f, nullptr, sum0 + 3072, sq0 + 3072, NB, F1, F2);
    bn_finalize<<<4, 256, 0, stream>>>(sum0 + 3072, sq0 + 3072, dg2, db2, sc0 + 3072, sh0 + 3072, F1);

    gemm1f<true, true, false><<<dim3(NB / 256, DH / 256), 512, 0, stream>>>(
        Y2f, D3t, sc0 + 3072, sh0 + 3072, out + HR_OFF, db3, nullptr, nullptr, NB, DH, F1);
}